// Round 12
// baseline (38.431 us; speedup 1.0000x reference)
//
#include <hip/hip_runtime.h>

// BayesPosLinear, fully-coalesced fused MFMA (R12):
//   out[s,b,o] = sum_i input[s,b,i] * exp(w_mu[o,i] + (1e-6+softplus(w_std_eta[o,i]))*eps_w[b,o,i])
//                + (b_mu[o] + (1e-6+softplus(b_std_eta[o]))*eps_b[b,o])
//   + KL(w), KL(b).
// S=16, B=32, IN=1024, OUT=1024.
//
// R12 (from R11's 37.7us): cut VMEM issue count + barriers in the fused kernel.
//  - eps loads: 8x dwordx4 (1KB/instr; lanes 0-31 -> row 2j, lanes 32-63 -> row 2j+1)
//    instead of 16x dwordx2. Same 16B-granular XOR swizzle into wave-private LDS.
//  - barrier diet: eps staging is wave-private (lgkmcnt ordering, no barrier);
//    each wave overlays its acc f32x4 into its OWN 8KB region -> single
//    __syncthreads() in the whole kernel (before the cross-wave reduce).
//  - everything else = R11 verified: frag-ordered tbl, frag-ordered a_ws, K-split-8,
//    (512,4), grid 2049 (block 2048 = KL finalize).

constexpr int S_ = 16, B_ = 32, IN_ = 1024, OUT_ = 1024;

typedef __bf16 bf16x8 __attribute__((ext_vector_type(8)));
typedef float  f32x4  __attribute__((ext_vector_type(4)));

__device__ __forceinline__ float softplus_f(float x) {
    float e = __expf(-fabsf(x));
    return fmaxf(x, 0.0f) + __logf(1.0f + e);
}

__device__ __forceinline__ unsigned bf16_hi(float x) {   // round, keep high 16
    return (__float_as_uint(x) + 0x8000u) & 0xffff0000u;
}

// ---------------- K1: frag-ordered packed table + klw partials (blocks 0-1023) ----
//                     input -> bf16 A-frags (blocks 1024-1055)
__global__ __launch_bounds__(256) void bpl_pre2(
    const float* __restrict__ input,   // [S,B,IN]
    const float* __restrict__ w_mu, const float* __restrict__ w_eta,
    unsigned* __restrict__ tbl_f,      // 4MB frag-ordered
    __bf16* __restrict__ a_ws,         // [B][2048][8]
    float* __restrict__ klw_part)      // [1024]
{
    const int tid = threadIdx.x;

    if (blockIdx.x >= 1024) {          // ---- A-frag staging (verified R7+) ----
        const int b = blockIdx.x - 1024;
        #pragma unroll
        for (int j = 0; j < 8; ++j) {
            const int c  = tid + j * 256;
            const int k0 = ((c >> 6) << 5) | (((c >> 4) & 3) << 3);
            const int s  = c & 15;
            const float* src = input + ((size_t)s * B_ + b) * IN_ + k0;
            const float4 x0 = *reinterpret_cast<const float4*>(src);
            const float4 x1 = *reinterpret_cast<const float4*>(src + 4);
            bf16x8 v;
            v[0] = (__bf16)x0.x; v[1] = (__bf16)x0.y; v[2] = (__bf16)x0.z; v[3] = (__bf16)x0.w;
            v[4] = (__bf16)x1.x; v[5] = (__bf16)x1.y; v[6] = (__bf16)x1.z; v[7] = (__bf16)x1.w;
            *reinterpret_cast<bf16x8*>(&a_ws[(size_t)b * 16384 + (size_t)c * 8]) = v;
        }
        return;
    }

    __shared__ float red[4];
    const int wid  = tid >> 6;
    const int lane = tid & 63;
    const int o    = blockIdx.x;
    const int ot   = o >> 4;
    const int on   = o & 15;

    const size_t base = (size_t)o * IN_ + tid * 4;
    const float4 mu = *reinterpret_cast<const float4*>(&w_mu[base]);
    const float4 et = *reinterpret_cast<const float4*>(&w_eta[base]);
    const float m[4] = {mu.x, mu.y, mu.z, mu.w};
    const float e[4] = {et.x, et.y, et.z, et.w};

    float local = 0.0f;
    #pragma unroll
    for (int j = 0; j < 4; ++j) {
        const int   i   = tid * 4 + j;
        const float sp  = __logf(1.0f + __expf(e[j])) + 1e-6f;  // w_eta in [-4,-2]
        const float spl = sp * 1.44269504f;                      // *log2(e)
        const float emu = __expf(m[j]);
        const unsigned pk = bf16_hi(emu) | (bf16_hi(spl) >> 16);
        const int kt  = i >> 5;
        const int kg0 = (i >> 3) & 3;
        const int jj  = i & 7;
        const int ln  = kg0 * 16 + on;
        tbl_f[(((size_t)ot * 32 + kt) * 64 + ln) * 8 + jj] = pk;
        local += -__logf(sp) + 0.5f * fmaf(sp, sp, m[j] * m[j]) - 0.5f;
    }

    #pragma unroll
    for (int off = 32; off > 0; off >>= 1) local += __shfl_xor(local, off, 64);
    if (lane == 0) red[wid] = local;
    __syncthreads();
    if (tid == 0) klw_part[blockIdx.x] = red[0] + red[1] + red[2] + red[3];
}

// ---------------- K2: fused GEMM (blocks 0-2047) + klfin (block 2048) ----------
__global__ __launch_bounds__(512, 4) void bpl_fused(
    const unsigned* __restrict__ tbl_f,// frag-ordered table
    const __bf16* __restrict__ a_ws,   // [B][2048][8]
    const float* __restrict__ eps_w,   // [B,OUT,IN]
    const float* __restrict__ b_mu,    // [OUT]
    const float* __restrict__ b_eta,   // [OUT]
    const float* __restrict__ eps_b,   // [B,OUT]
    const float* __restrict__ klw_part,// [1024]
    float* __restrict__ out,           // [S,B,OUT]
    float* __restrict__ kl)            // kl[0], kl[1]
{
    const int blk = blockIdx.x;
    const int tid = threadIdx.x;

    if (blk == 2048) {                 // ---- klfin (512 threads) ----
        __shared__ float kred[16];
        const int wid  = tid >> 6;
        const int lane = tid & 63;
        float lw = klw_part[tid] + klw_part[tid + 512];
        float lb;
        {
            const int o = tid;               // 0..511
            const float sd0 = softplus_f(b_eta[o]) + 1e-6f;
            const float m0  = b_mu[o];
            const float sd1 = softplus_f(b_eta[o + 512]) + 1e-6f;
            const float m1  = b_mu[o + 512];
            lb = (-__logf(sd0) + 0.5f * fmaf(sd0, sd0, m0 * m0) - 0.5f)
               + (-__logf(sd1) + 0.5f * fmaf(sd1, sd1, m1 * m1) - 0.5f);
        }
        #pragma unroll
        for (int off = 32; off > 0; off >>= 1) {
            lw += __shfl_xor(lw, off, 64);
            lb += __shfl_xor(lb, off, 64);
        }
        if (lane == 0) { kred[wid] = lw; kred[8 + wid] = lb; }
        __syncthreads();
        if (tid == 0) {
            float tw = 0.0f, tb = 0.0f;
            #pragma unroll
            for (int k = 0; k < 8; ++k) { tw += kred[k]; tb += kred[8 + k]; }
            kl[0] = tw; kl[1] = tb;
        }
        return;
    }

    __shared__ __align__(16) float smem[16384];   // 64KB: 8 waves x 8KB wave-private

    const int xcd = blk & 7;
    const int r_  = blk >> 3;          // 0..255
    const int b   = r_ & 31;
    const int otl = r_ >> 5;           // 0..7
    const int o_base = xcd * 128 + otl * 16;
    const int ot_g   = o_base >> 4;    // global o-tile 0..63

    const int kq   = tid >> 6;         // 0..7: K-eighth (wave id)
    const int lane = tid & 63;
    const int on   = lane & 15;
    const int kg0  = lane >> 4;        // 0..3

    // ---- issue ALL global loads up front (coalesced) ----
    // eps: 8x dwordx4; load j covers rows 2j (lanes 0-31) and 2j+1 (lanes 32-63),
    // 1KB contiguous-per-row-pair. Row r = o-row o_base+r, cols kq*128 + (lane&31)*4.
    const float* eps_base = eps_w + ((size_t)(b * 1024 + o_base)) * 1024 + kq * 128;
    const int rlo = lane >> 5;                    // 0 or 1
    const int cq  = lane & 31;
    float4 ev[8];
    #pragma unroll
    for (int j = 0; j < 8; ++j) {
        const int r = 2 * j + rlo;
        ev[j] = *reinterpret_cast<const float4*>(eps_base + (size_t)r * 1024 + cq * 4);
    }

    const unsigned* tf = tbl_f + (((size_t)ot_g * 32 + kq * 4) * 64 + lane) * 8;
    uint4 t0[4], t1[4];
    #pragma unroll
    for (int t = 0; t < 4; ++t) {
        t0[t] = *reinterpret_cast<const uint4*>(tf + t * 512);
        t1[t] = *reinterpret_cast<const uint4*>(tf + t * 512 + 4);
    }

    const __bf16* ap = a_ws + (size_t)b * 16384 + (size_t)(kq * 4) * 512 + lane * 8;
    bf16x8 av[4];
    #pragma unroll
    for (int t = 0; t < 4; ++t)
        av[t] = *reinterpret_cast<const bf16x8*>(ap + t * 512);

    // ---- stage eps into wave-PRIVATE LDS (8KB), 16B-granular XOR swizzle ----
    // col-byte c of row r stored at byte c ^ ((r&7)<<4). No barrier: wave-local,
    // lgkmcnt ordering covers write->read within the wave.
    char* wbase = (char*)(smem + kq * 2048);      // 8KB per wave
    #pragma unroll
    for (int j = 0; j < 8; ++j) {
        const int r    = 2 * j + rlo;
        const int byte = (cq * 16) ^ ((r & 7) << 4);
        *reinterpret_cast<float4*>(wbase + r * 512 + byte) = ev[j];
    }

    // ---- 4 k-steps: LDS B-frag + reg tbl/a -> MFMA ----
    f32x4 acc = {0.0f, 0.0f, 0.0f, 0.0f};
    const int sw = (on & 7) << 4;
    #pragma unroll
    for (int t = 0; t < 4; ++t) {
        const f32x4 e0 = *reinterpret_cast<const f32x4*>(
            wbase + on * 512 + ((t * 128 + kg0 * 32) ^ sw));
        const f32x4 e1 = *reinterpret_cast<const f32x4*>(
            wbase + on * 512 + ((t * 128 + kg0 * 32 + 16) ^ sw));

        const unsigned uu[8] = {t0[t].x, t0[t].y, t0[t].z, t0[t].w,
                                t1[t].x, t1[t].y, t1[t].z, t1[t].w};
        const float    ee[8] = {e0[0], e0[1], e0[2], e0[3], e1[0], e1[1], e1[2], e1[3]};

        bf16x8 bfrag;
        #pragma unroll
        for (int q = 0; q < 8; ++q) {
            const float emu = __uint_as_float(uu[q] & 0xffff0000u);
            const float spl = __uint_as_float(uu[q] << 16);
            bfrag[q] = (__bf16)(emu * exp2f(spl * ee[q]));
        }
        acc = __builtin_amdgcn_mfma_f32_16x16x32_bf16(av[t], bfrag, acc, 0, 0, 0);
    }

    // ---- overlay acc into the wave's OWN region; ONE barrier; cross-wave reduce ----
    *reinterpret_cast<f32x4*>(&smem[kq * 2048 + lane * 4]) = acc;
    __syncthreads();

    if (tid < 256) {
        const int s  = tid >> 4;       // 0..15
        const int ol = tid & 15;
        const int srcLane = ((s >> 2) << 4) | ol;
        const int rr = s & 3;
        float v = 0.0f;
        #pragma unroll
        for (int k8 = 0; k8 < 8; ++k8)
            v += smem[k8 * 2048 + srcLane * 4 + rr];
        const int oo = o_base + ol;
        const float bias = fmaf(softplus_f(b_eta[oo]) + 1e-6f,
                                eps_b[(size_t)b * OUT_ + oo], b_mu[oo]);
        out[((size_t)s * B_ + b) * OUT_ + oo] = v + bias;
    }
}

// ---------------- fallback (R6/R7 verified path, no ws) ----------------
__global__ __launch_bounds__(256) void bpl_pre_fb(
    const float* __restrict__ w_mu, const float* __restrict__ w_eta,
    const float* __restrict__ b_mu, const float* __restrict__ b_eta,
    float* __restrict__ kl)
{
    __shared__ float red[4];
    const int tid  = threadIdx.x;
    const int wid  = tid >> 6;
    const int lane = tid & 63;

    const size_t base = (size_t)blockIdx.x * IN_ + tid * 4;
    const float4 mu = *reinterpret_cast<const float4*>(&w_mu[base]);
    const float4 et = *reinterpret_cast<const float4*>(&w_eta[base]);
    const float m[4] = {mu.x, mu.y, mu.z, mu.w};
    const float e[4] = {et.x, et.y, et.z, et.w};

    float local = 0.0f;
    #pragma unroll
    for (int j = 0; j < 4; ++j) {
        const float sp = __logf(1.0f + __expf(e[j])) + 1e-6f;
        local += -__logf(sp) + 0.5f * fmaf(sp, sp, m[j] * m[j]) - 0.5f;
    }
    #pragma unroll
    for (int off = 32; off > 0; off >>= 1) local += __shfl_xor(local, off, 64);
    if (lane == 0) red[wid] = local;
    __syncthreads();
    if (tid == 0) atomicAdd(&kl[0], red[0] + red[1] + red[2] + red[3]);

    if (blockIdx.x != 0) return;
    float lb = 0.0f;
    #pragma unroll
    for (int j = 0; j < 4; ++j) {
        const int idx = tid * 4 + j;
        const float sd = softplus_f(b_eta[idx]) + 1e-6f;
        const float mm = b_mu[idx];
        lb += -__logf(sd) + 0.5f * fmaf(sd, sd, mm * mm) - 0.5f;
    }
    #pragma unroll
    for (int off = 32; off > 0; off >>= 1) lb += __shfl_xor(lb, off, 64);
    __syncthreads();
    if (lane == 0) red[wid] = lb;
    __syncthreads();
    if (tid == 0) atomicAdd(&kl[1], red[0] + red[1] + red[2] + red[3]);
}

__global__ __launch_bounds__(256, 4) void bpl_mfma_fb(
    const float* __restrict__ input, const float* __restrict__ w_mu,
    const float* __restrict__ w_eta, const float* __restrict__ b_mu,
    const float* __restrict__ b_eta, const float* __restrict__ eps_w,
    const float* __restrict__ eps_b, float* __restrict__ out)
{
    __shared__ __align__(16) __bf16 alds[16384];

    const int blk = blockIdx.x;
    const int xcd = blk & 7;
    const int r_  = blk >> 3;
    const int b   = r_ & 31;
    const int oh  = r_ >> 5;
    const int o_base = (xcd * 2 + oh) * 64;

    const int tid  = threadIdx.x;
    const int wid  = tid >> 6;
    const int lane = tid & 63;

    #pragma unroll
    for (int j = 0; j < 8; ++j) {
        const int c   = tid + j * 256;
        const int s   = c & 15;
        const int kgg = ((c >> 6) << 2) | ((c >> 4) & 3);
        const float* src = input + ((size_t)s * B_ + b) * IN_ + kgg * 8;
        const float4 x0 = *reinterpret_cast<const float4*>(src);
        const float4 x1 = *reinterpret_cast<const float4*>(src + 4);
        bf16x8 v;
        v[0] = (__bf16)x0.x; v[1] = (__bf16)x0.y; v[2] = (__bf16)x0.z; v[3] = (__bf16)x0.w;
        v[4] = (__bf16)x1.x; v[5] = (__bf16)x1.y; v[6] = (__bf16)x1.z; v[7] = (__bf16)x1.w;
        *reinterpret_cast<bf16x8*>(&alds[c * 8]) = v;
    }
    __syncthreads();

    const int on    = lane & 15;
    const int kg0   = lane >> 4;
    const int o_row = o_base + wid * 16 + on;

    const float* __restrict__ mu_p = w_mu  + (size_t)o_row * IN_ + kg0 * 8;
    const float* __restrict__ et_p = w_eta + (size_t)o_row * IN_ + kg0 * 8;
    const float* __restrict__ ep_p = eps_w + ((size_t)b * OUT_ + o_row) * IN_ + kg0 * 8;
    const __bf16* __restrict__ a_p = alds + lane * 8;

    f32x4 acc = {0.0f, 0.0f, 0.0f, 0.0f};
    #pragma unroll
    for (int kt = 0; kt < 32; ++kt) {
        const int i_ = kt * 32;
        const float4 m0 = *reinterpret_cast<const float4*>(mu_p + i_);
        const float4 m1 = *reinterpret_cast<const float4*>(mu_p + i_ + 4);
        const float4 s0 = *reinterpret_cast<const float4*>(et_p + i_);
        const float4 s1 = *reinterpret_cast<const float4*>(et_p + i_ + 4);
        const float4 e0 = *reinterpret_cast<const float4*>(ep_p + i_);
        const float4 e1 = *reinterpret_cast<const float4*>(ep_p + i_ + 4);
        const float mm[8] = {m0.x, m0.y, m0.z, m0.w, m1.x, m1.y, m1.z, m1.w};
        const float ss[8] = {s0.x, s0.y, s0.z, s0.w, s1.x, s1.y, s1.z, s1.w};
        const float ee[8] = {e0.x, e0.y, e0.z, e0.w, e1.x, e1.y, e1.z, e1.w};
        bf16x8 bfrag;
        #pragma unroll
        for (int q = 0; q < 8; ++q) {
            const float sp_ = __logf(1.0f + __expf(ss[q])) + 1e-6f;
            bfrag[q] = (__bf16)__expf(fmaf(sp_, ee[q], mm[q]));
        }
        const bf16x8 afrag = *reinterpret_cast<const bf16x8*>(a_p + kt * 512);
        acc = __builtin_amdgcn_mfma_f32_16x16x32_bf16(afrag, bfrag, acc, 0, 0, 0);
    }

    const float bias = fmaf(softplus_f(b_eta[o_row]) + 1e-6f,
                            eps_b[(size_t)b * OUT_ + o_row], b_mu[o_row]);
    #pragma unroll
    for (int rr = 0; rr < 4; ++rr) {
        const int s = kg0 * 4 + rr;
        out[((size_t)s * B_ + b) * OUT_ + o_row] = acc[rr] + bias;
    }
}

extern "C" void kernel_launch(void* const* d_in, const int* in_sizes, int n_in,
                              void* d_out, int out_size, void* d_ws, size_t ws_size,
                              hipStream_t stream)
{
    const float* input = (const float*)d_in[0];
    const float* w_mu  = (const float*)d_in[1];
    const float* w_eta = (const float*)d_in[2];
    const float* b_mu  = (const float*)d_in[3];
    const float* b_eta = (const float*)d_in[4];
    const float* eps_w = (const float*)d_in[5];
    const float* eps_b = (const float*)d_in[6];

    float* out = (float*)d_out;
    float* kl  = out + (size_t)S_ * B_ * OUT_;   // offsets 524288, 524289

    // ws layout
    const size_t TBL_OFF = 0;                                  // 4 MB frag-ordered table
    const size_t A_OFF   = (size_t)4 * 1024 * 1024;            // 1 MB bf16 a-frags
    const size_t KLP_OFF = (size_t)5 * 1024 * 1024;            // 4 KB kl_w partials
    const size_t NEED    = KLP_OFF + 4096;

    if (ws_size >= NEED) {
        unsigned* tbl  = (unsigned*)((char*)d_ws + TBL_OFF);
        __bf16*   a_ws = (__bf16*)((char*)d_ws + A_OFF);
        float*    klp  = (float*)((char*)d_ws + KLP_OFF);

        bpl_pre2<<<1056, 256, 0, stream>>>(input, w_mu, w_eta, tbl, a_ws, klp);
        bpl_fused<<<2049, 512, 0, stream>>>(tbl, a_ws, eps_w, b_mu, b_eta, eps_b,
                                            klp, out, kl);
    } else {
        hipMemsetAsync(kl, 0, 2 * sizeof(float), stream);
        bpl_pre_fb<<<1024, 256, 0, stream>>>(w_mu, w_eta, b_mu, b_eta, kl);
        bpl_mfma_fb<<<512, 256, 0, stream>>>(input, w_mu, w_eta, b_mu, b_eta,
                                             eps_w, eps_b, out);
    }
}

// Round 13
// 38.142 us; speedup vs baseline: 1.0076x; 1.0076x over previous
//
#include <hip/hip_runtime.h>

// BayesPosLinear, fused MFMA, batch-paired blocks (R13):
//   out[s,b,o] = sum_i input[s,b,i] * exp(w_mu[o,i] + (1e-6+softplus(w_std_eta[o,i]))*eps_w[b,o,i])
//                + (b_mu[o] + (1e-6+softplus(b_std_eta[o]))*eps_b[b,o])
//   + KL(w), KL(b).
// S=16, B=32, IN=1024, OUT=1024.
//
// R13 (from R11/R12's ~38us): one block = one 16-o tile x TWO batches (b0,b1).
//  - tbl regs reused for both batches: tbl L2 traffic halves (16->8MB).
//  - eps(b1) global loads issue BEFORE b0's compute phase -> latency hidden under
//    real work (not just other loads).
//  - grid 1025 (1024 GEMM + klfin): 2 residency rounds at 2 blocks/CU instead of 4.
//  - wave-private 8KB eps region reused b0->b1 (per-wave DS ordering, no barrier).
//  - everything else verified from R11/R12: frag-ordered tbl/a_ws, K-split-8,
//    XOR-swizzled LDS, (512,4), single block-wide barrier before the reduce.

constexpr int S_ = 16, B_ = 32, IN_ = 1024, OUT_ = 1024;

typedef __bf16 bf16x8 __attribute__((ext_vector_type(8)));
typedef float  f32x4  __attribute__((ext_vector_type(4)));

__device__ __forceinline__ float softplus_f(float x) {
    float e = __expf(-fabsf(x));
    return fmaxf(x, 0.0f) + __logf(1.0f + e);
}

__device__ __forceinline__ unsigned bf16_hi(float x) {   // round, keep high 16
    return (__float_as_uint(x) + 0x8000u) & 0xffff0000u;
}

// ---------------- K1: frag-ordered packed table + klw partials (blocks 0-1023) ----
//                     input -> bf16 A-frags (blocks 1024-1055)
__global__ __launch_bounds__(256) void bpl_pre2(
    const float* __restrict__ input,   // [S,B,IN]
    const float* __restrict__ w_mu, const float* __restrict__ w_eta,
    unsigned* __restrict__ tbl_f,      // 4MB frag-ordered
    __bf16* __restrict__ a_ws,         // [B][2048][8]
    float* __restrict__ klw_part)      // [1024]
{
    const int tid = threadIdx.x;

    if (blockIdx.x >= 1024) {          // ---- A-frag staging (verified R7+) ----
        const int b = blockIdx.x - 1024;
        #pragma unroll
        for (int j = 0; j < 8; ++j) {
            const int c  = tid + j * 256;
            const int k0 = ((c >> 6) << 5) | (((c >> 4) & 3) << 3);
            const int s  = c & 15;
            const float* src = input + ((size_t)s * B_ + b) * IN_ + k0;
            const float4 x0 = *reinterpret_cast<const float4*>(src);
            const float4 x1 = *reinterpret_cast<const float4*>(src + 4);
            bf16x8 v;
            v[0] = (__bf16)x0.x; v[1] = (__bf16)x0.y; v[2] = (__bf16)x0.z; v[3] = (__bf16)x0.w;
            v[4] = (__bf16)x1.x; v[5] = (__bf16)x1.y; v[6] = (__bf16)x1.z; v[7] = (__bf16)x1.w;
            *reinterpret_cast<bf16x8*>(&a_ws[(size_t)b * 16384 + (size_t)c * 8]) = v;
        }
        return;
    }

    __shared__ float red[4];
    const int wid  = tid >> 6;
    const int lane = tid & 63;
    const int o    = blockIdx.x;
    const int ot   = o >> 4;
    const int on   = o & 15;

    const size_t base = (size_t)o * IN_ + tid * 4;
    const float4 mu = *reinterpret_cast<const float4*>(&w_mu[base]);
    const float4 et = *reinterpret_cast<const float4*>(&w_eta[base]);
    const float m[4] = {mu.x, mu.y, mu.z, mu.w};
    const float e[4] = {et.x, et.y, et.z, et.w};

    float local = 0.0f;
    #pragma unroll
    for (int j = 0; j < 4; ++j) {
        const int   i   = tid * 4 + j;
        const float sp  = __logf(1.0f + __expf(e[j])) + 1e-6f;  // w_eta in [-4,-2]
        const float spl = sp * 1.44269504f;                      // *log2(e)
        const float emu = __expf(m[j]);
        const unsigned pk = bf16_hi(emu) | (bf16_hi(spl) >> 16);
        const int kt  = i >> 5;
        const int kg0 = (i >> 3) & 3;
        const int jj  = i & 7;
        const int ln  = kg0 * 16 + on;
        tbl_f[(((size_t)ot * 32 + kt) * 64 + ln) * 8 + jj] = pk;
        local += -__logf(sp) + 0.5f * fmaf(sp, sp, m[j] * m[j]) - 0.5f;
    }

    #pragma unroll
    for (int off = 32; off > 0; off >>= 1) local += __shfl_xor(local, off, 64);
    if (lane == 0) red[wid] = local;
    __syncthreads();
    if (tid == 0) klw_part[blockIdx.x] = red[0] + red[1] + red[2] + red[3];
}

// ---------------- K2: fused GEMM (blocks 0-1023, b-pairs) + klfin (block 1024) ----
__global__ __launch_bounds__(512, 4) void bpl_fused(
    const unsigned* __restrict__ tbl_f,// frag-ordered table
    const __bf16* __restrict__ a_ws,   // [B][2048][8]
    const float* __restrict__ eps_w,   // [B,OUT,IN]
    const float* __restrict__ b_mu,    // [OUT]
    const float* __restrict__ b_eta,   // [OUT]
    const float* __restrict__ eps_b,   // [B,OUT]
    const float* __restrict__ klw_part,// [1024]
    float* __restrict__ out,           // [S,B,OUT]
    float* __restrict__ kl)            // kl[0], kl[1]
{
    const int blk = blockIdx.x;
    const int tid = threadIdx.x;

    if (blk == 1024) {                 // ---- klfin (512 threads) ----
        __shared__ float kred[16];
        const int wid  = tid >> 6;
        const int lane = tid & 63;
        float lw = klw_part[tid] + klw_part[tid + 512];
        float lb;
        {
            const int o = tid;               // 0..511
            const float sd0 = softplus_f(b_eta[o]) + 1e-6f;
            const float m0  = b_mu[o];
            const float sd1 = softplus_f(b_eta[o + 512]) + 1e-6f;
            const float m1  = b_mu[o + 512];
            lb = (-__logf(sd0) + 0.5f * fmaf(sd0, sd0, m0 * m0) - 0.5f)
               + (-__logf(sd1) + 0.5f * fmaf(sd1, sd1, m1 * m1) - 0.5f);
        }
        #pragma unroll
        for (int off = 32; off > 0; off >>= 1) {
            lw += __shfl_xor(lw, off, 64);
            lb += __shfl_xor(lb, off, 64);
        }
        if (lane == 0) { kred[wid] = lw; kred[8 + wid] = lb; }
        __syncthreads();
        if (tid == 0) {
            float tw = 0.0f, tb = 0.0f;
            #pragma unroll
            for (int k = 0; k < 8; ++k) { tw += kred[k]; tb += kred[8 + k]; }
            kl[0] = tw; kl[1] = tb;
        }
        return;
    }

    __shared__ __align__(16) float smem[16384];   // 64KB: 8 waves x 8KB wave-private

    const int xcd = blk & 7;
    const int r_  = blk >> 3;          // 0..127
    const int bp  = r_ & 15;           // b-pair 0..15
    const int otl = r_ >> 4;           // 0..7
    const int b0  = bp * 2;
    const int b1  = b0 + 1;
    const int o_base = xcd * 128 + otl * 16;
    const int ot_g   = o_base >> 4;    // global o-tile 0..63

    const int kq   = tid >> 6;         // 0..7: K-eighth (wave id)
    const int lane = tid & 63;
    const int on   = lane & 15;
    const int kg0  = lane >> 4;        // 0..3
    const int rlo  = lane >> 5;        // 0 or 1
    const int cq   = lane & 31;

    // ---- tbl + A-frags for both batches (issue first) ----
    const unsigned* tf = tbl_f + (((size_t)ot_g * 32 + kq * 4) * 64 + lane) * 8;
    uint4 t0[4], t1[4];
    #pragma unroll
    for (int t = 0; t < 4; ++t) {
        t0[t] = *reinterpret_cast<const uint4*>(tf + t * 512);
        t1[t] = *reinterpret_cast<const uint4*>(tf + t * 512 + 4);
    }
    const __bf16* ap0 = a_ws + (size_t)b0 * 16384 + (size_t)(kq * 4) * 512 + lane * 8;
    const __bf16* ap1 = a_ws + (size_t)b1 * 16384 + (size_t)(kq * 4) * 512 + lane * 8;
    bf16x8 av0[4], av1[4];
    #pragma unroll
    for (int t = 0; t < 4; ++t) {
        av0[t] = *reinterpret_cast<const bf16x8*>(ap0 + t * 512);
        av1[t] = *reinterpret_cast<const bf16x8*>(ap1 + t * 512);
    }

    // ---- eps(b0): 8x dwordx4 -> wave-private LDS (XOR swizzle) ----
    const float* eb0 = eps_w + ((size_t)(b0 * 1024 + o_base)) * 1024 + kq * 128;
    const float* eb1 = eps_w + ((size_t)(b1 * 1024 + o_base)) * 1024 + kq * 128;
    char* wbase = (char*)(smem + kq * 2048);      // 8KB per wave

    float4 ev[8];
    #pragma unroll
    for (int j = 0; j < 8; ++j)
        ev[j] = *reinterpret_cast<const float4*>(eb0 + (size_t)(2 * j + rlo) * 1024 + cq * 4);
    #pragma unroll
    for (int j = 0; j < 8; ++j) {
        const int r    = 2 * j + rlo;
        const int byte = (cq * 16) ^ ((r & 7) << 4);
        *reinterpret_cast<float4*>(wbase + r * 512 + byte) = ev[j];
    }

    // ---- issue eps(b1) loads NOW: latency hides under b0 compute ----
    float4 ev1[8];
    #pragma unroll
    for (int j = 0; j < 8; ++j)
        ev1[j] = *reinterpret_cast<const float4*>(eb1 + (size_t)(2 * j + rlo) * 1024 + cq * 4);

    // ---- compute b0 (4 k-steps) ----
    const int sw = (on & 7) << 4;
    f32x4 acc0 = {0.0f, 0.0f, 0.0f, 0.0f};
    #pragma unroll
    for (int t = 0; t < 4; ++t) {
        const f32x4 e0 = *reinterpret_cast<const f32x4*>(
            wbase + on * 512 + ((t * 128 + kg0 * 32) ^ sw));
        const f32x4 e1 = *reinterpret_cast<const f32x4*>(
            wbase + on * 512 + ((t * 128 + kg0 * 32 + 16) ^ sw));
        const unsigned uu[8] = {t0[t].x, t0[t].y, t0[t].z, t0[t].w,
                                t1[t].x, t1[t].y, t1[t].z, t1[t].w};
        const float    ee[8] = {e0[0], e0[1], e0[2], e0[3], e1[0], e1[1], e1[2], e1[3]};
        bf16x8 bfrag;
        #pragma unroll
        for (int q = 0; q < 8; ++q) {
            const float emu = __uint_as_float(uu[q] & 0xffff0000u);
            const float spl = __uint_as_float(uu[q] << 16);
            bfrag[q] = (__bf16)(emu * exp2f(spl * ee[q]));
        }
        acc0 = __builtin_amdgcn_mfma_f32_16x16x32_bf16(av0[t], bfrag, acc0, 0, 0, 0);
    }

    // ---- stage eps(b1) into the same wave-private region (per-wave DS order) ----
    #pragma unroll
    for (int j = 0; j < 8; ++j) {
        const int r    = 2 * j + rlo;
        const int byte = (cq * 16) ^ ((r & 7) << 4);
        *reinterpret_cast<float4*>(wbase + r * 512 + byte) = ev1[j];
    }

    // ---- compute b1 (4 k-steps) ----
    f32x4 acc1 = {0.0f, 0.0f, 0.0f, 0.0f};
    #pragma unroll
    for (int t = 0; t < 4; ++t) {
        const f32x4 e0 = *reinterpret_cast<const f32x4*>(
            wbase + on * 512 + ((t * 128 + kg0 * 32) ^ sw));
        const f32x4 e1 = *reinterpret_cast<const f32x4*>(
            wbase + on * 512 + ((t * 128 + kg0 * 32 + 16) ^ sw));
        const unsigned uu[8] = {t0[t].x, t0[t].y, t0[t].z, t0[t].w,
                                t1[t].x, t1[t].y, t1[t].z, t1[t].w};
        const float    ee[8] = {e0[0], e0[1], e0[2], e0[3], e1[0], e1[1], e1[2], e1[3]};
        bf16x8 bfrag;
        #pragma unroll
        for (int q = 0; q < 8; ++q) {
            const float emu = __uint_as_float(uu[q] & 0xffff0000u);
            const float spl = __uint_as_float(uu[q] << 16);
            bfrag[q] = (__bf16)(emu * exp2f(spl * ee[q]));
        }
        acc1 = __builtin_amdgcn_mfma_f32_16x16x32_bf16(av1[t], bfrag, acc1, 0, 0, 0);
    }

    // ---- overlay both accs into the wave's OWN region; ONE barrier; reduce ----
    *reinterpret_cast<f32x4*>(&smem[kq * 2048 + lane * 4]) = acc0;
    *reinterpret_cast<f32x4*>(&smem[kq * 2048 + 1024 + lane * 4]) = acc1;
    __syncthreads();

    {
        const int half = tid >> 8;         // 0: b0, 1: b1
        const int t8   = tid & 255;
        const int s    = t8 >> 4;          // 0..15
        const int ol   = t8 & 15;
        const int srcLane = ((s >> 2) << 4) | ol;
        const int rr = s & 3;
        const int off = half * 1024;
        float v = 0.0f;
        #pragma unroll
        for (int k8 = 0; k8 < 8; ++k8)
            v += smem[k8 * 2048 + off + srcLane * 4 + rr];
        const int bb = half ? b1 : b0;
        const int oo = o_base + ol;
        const float bias = fmaf(softplus_f(b_eta[oo]) + 1e-6f,
                                eps_b[(size_t)bb * OUT_ + oo], b_mu[oo]);
        out[((size_t)s * B_ + bb) * OUT_ + oo] = v + bias;
    }
}

// ---------------- fallback (R6/R7 verified path, no ws) ----------------
__global__ __launch_bounds__(256) void bpl_pre_fb(
    const float* __restrict__ w_mu, const float* __restrict__ w_eta,
    const float* __restrict__ b_mu, const float* __restrict__ b_eta,
    float* __restrict__ kl)
{
    __shared__ float red[4];
    const int tid  = threadIdx.x;
    const int wid  = tid >> 6;
    const int lane = tid & 63;

    const size_t base = (size_t)blockIdx.x * IN_ + tid * 4;
    const float4 mu = *reinterpret_cast<const float4*>(&w_mu[base]);
    const float4 et = *reinterpret_cast<const float4*>(&w_eta[base]);
    const float m[4] = {mu.x, mu.y, mu.z, mu.w};
    const float e[4] = {et.x, et.y, et.z, et.w};

    float local = 0.0f;
    #pragma unroll
    for (int j = 0; j < 4; ++j) {
        const float sp = __logf(1.0f + __expf(e[j])) + 1e-6f;
        local += -__logf(sp) + 0.5f * fmaf(sp, sp, m[j] * m[j]) - 0.5f;
    }
    #pragma unroll
    for (int off = 32; off > 0; off >>= 1) local += __shfl_xor(local, off, 64);
    if (lane == 0) red[wid] = local;
    __syncthreads();
    if (tid == 0) atomicAdd(&kl[0], red[0] + red[1] + red[2] + red[3]);

    if (blockIdx.x != 0) return;
    float lb = 0.0f;
    #pragma unroll
    for (int j = 0; j < 4; ++j) {
        const int idx = tid * 4 + j;
        const float sd = softplus_f(b_eta[idx]) + 1e-6f;
        const float mm = b_mu[idx];
        lb += -__logf(sd) + 0.5f * fmaf(sd, sd, mm * mm) - 0.5f;
    }
    #pragma unroll
    for (int off = 32; off > 0; off >>= 1) lb += __shfl_xor(lb, off, 64);
    __syncthreads();
    if (lane == 0) red[wid] = lb;
    __syncthreads();
    if (tid == 0) atomicAdd(&kl[1], red[0] + red[1] + red[2] + red[3]);
}

__global__ __launch_bounds__(256, 4) void bpl_mfma_fb(
    const float* __restrict__ input, const float* __restrict__ w_mu,
    const float* __restrict__ w_eta, const float* __restrict__ b_mu,
    const float* __restrict__ b_eta, const float* __restrict__ eps_w,
    const float* __restrict__ eps_b, float* __restrict__ out)
{
    __shared__ __align__(16) __bf16 alds[16384];

    const int blk = blockIdx.x;
    const int xcd = blk & 7;
    const int r_  = blk >> 3;
    const int b   = r_ & 31;
    const int oh  = r_ >> 5;
    const int o_base = (xcd * 2 + oh) * 64;

    const int tid  = threadIdx.x;
    const int wid  = tid >> 6;
    const int lane = tid & 63;

    #pragma unroll
    for (int j = 0; j < 8; ++j) {
        const int c   = tid + j * 256;
        const int s   = c & 15;
        const int kgg = ((c >> 6) << 2) | ((c >> 4) & 3);
        const float* src = input + ((size_t)s * B_ + b) * IN_ + kgg * 8;
        const float4 x0 = *reinterpret_cast<const float4*>(src);
        const float4 x1 = *reinterpret_cast<const float4*>(src + 4);
        bf16x8 v;
        v[0] = (__bf16)x0.x; v[1] = (__bf16)x0.y; v[2] = (__bf16)x0.z; v[3] = (__bf16)x0.w;
        v[4] = (__bf16)x1.x; v[5] = (__bf16)x1.y; v[6] = (__bf16)x1.z; v[7] = (__bf16)x1.w;
        *reinterpret_cast<bf16x8*>(&alds[c * 8]) = v;
    }
    __syncthreads();

    const int on    = lane & 15;
    const int kg0   = lane >> 4;
    const int o_row = o_base + wid * 16 + on;

    const float* __restrict__ mu_p = w_mu  + (size_t)o_row * IN_ + kg0 * 8;
    const float* __restrict__ et_p = w_eta + (size_t)o_row * IN_ + kg0 * 8;
    const float* __restrict__ ep_p = eps_w + ((size_t)b * OUT_ + o_row) * IN_ + kg0 * 8;
    const __bf16* __restrict__ a_p = alds + lane * 8;

    f32x4 acc = {0.0f, 0.0f, 0.0f, 0.0f};
    #pragma unroll
    for (int kt = 0; kt < 32; ++kt) {
        const int i_ = kt * 32;
        const float4 m0 = *reinterpret_cast<const float4*>(mu_p + i_);
        const float4 m1 = *reinterpret_cast<const float4*>(mu_p + i_ + 4);
        const float4 s0 = *reinterpret_cast<const float4*>(et_p + i_);
        const float4 s1 = *reinterpret_cast<const float4*>(et_p + i_ + 4);
        const float4 e0 = *reinterpret_cast<const float4*>(ep_p + i_);
        const float4 e1 = *reinterpret_cast<const float4*>(ep_p + i_ + 4);
        const float mm[8] = {m0.x, m0.y, m0.z, m0.w, m1.x, m1.y, m1.z, m1.w};
        const float ss[8] = {s0.x, s0.y, s0.z, s0.w, s1.x, s1.y, s1.z, s1.w};
        const float ee[8] = {e0.x, e0.y, e0.z, e0.w, e1.x, e1.y, e1.z, e1.w};
        bf16x8 bfrag;
        #pragma unroll
        for (int q = 0; q < 8; ++q) {
            const float sp_ = __logf(1.0f + __expf(ss[q])) + 1e-6f;
            bfrag[q] = (__bf16)__expf(fmaf(sp_, ee[q], mm[q]));
        }
        const bf16x8 afrag = *reinterpret_cast<const bf16x8*>(a_p + kt * 512);
        acc = __builtin_amdgcn_mfma_f32_16x16x32_bf16(afrag, bfrag, acc, 0, 0, 0);
    }

    const float bias = fmaf(softplus_f(b_eta[o_row]) + 1e-6f,
                            eps_b[(size_t)b * OUT_ + o_row], b_mu[o_row]);
    #pragma unroll
    for (int rr = 0; rr < 4; ++rr) {
        const int s = kg0 * 4 + rr;
        out[((size_t)s * B_ + b) * OUT_ + o_row] = acc[rr] + bias;
    }
}

extern "C" void kernel_launch(void* const* d_in, const int* in_sizes, int n_in,
                              void* d_out, int out_size, void* d_ws, size_t ws_size,
                              hipStream_t stream)
{
    const float* input = (const float*)d_in[0];
    const float* w_mu  = (const float*)d_in[1];
    const float* w_eta = (const float*)d_in[2];
    const float* b_mu  = (const float*)d_in[3];
    const float* b_eta = (const float*)d_in[4];
    const float* eps_w = (const float*)d_in[5];
    const float* eps_b = (const float*)d_in[6];

    float* out = (float*)d_out;
    float* kl  = out + (size_t)S_ * B_ * OUT_;   // offsets 524288, 524289

    // ws layout
    const size_t TBL_OFF = 0;                                  // 4 MB frag-ordered table
    const size_t A_OFF   = (size_t)4 * 1024 * 1024;            // 1 MB bf16 a-frags
    const size_t KLP_OFF = (size_t)5 * 1024 * 1024;            // 4 KB kl_w partials
    const size_t NEED    = KLP_OFF + 4096;

    if (ws_size >= NEED) {
        unsigned* tbl  = (unsigned*)((char*)d_ws + TBL_OFF);
        __bf16*   a_ws = (__bf16*)((char*)d_ws + A_OFF);
        float*    klp  = (float*)((char*)d_ws + KLP_OFF);

        bpl_pre2<<<1056, 256, 0, stream>>>(input, w_mu, w_eta, tbl, a_ws, klp);
        bpl_fused<<<1025, 512, 0, stream>>>(tbl, a_ws, eps_w, b_mu, b_eta, eps_b,
                                            klp, out, kl);
    } else {
        hipMemsetAsync(kl, 0, 2 * sizeof(float), stream);
        bpl_pre_fb<<<1024, 256, 0, stream>>>(w_mu, w_eta, b_mu, b_eta, kl);
        bpl_mfma_fb<<<512, 256, 0, stream>>>(input, w_mu, w_eta, b_mu, b_eta,
                                             eps_w, eps_b, out);
    }
}

// Round 14
// 37.266 us; speedup vs baseline: 1.0313x; 1.0235x over previous
//
#include <hip/hip_runtime.h>

// BayesPosLinear, fully-coalesced fused MFMA (R14 = R11-best + pre2 XCD alignment):
//   out[s,b,o] = sum_i input[s,b,i] * exp(w_mu[o,i] + (1e-6+softplus(w_std_eta[o,i]))*eps_w[b,o,i])
//                + (b_mu[o] + (1e-6+softplus(b_std_eta[o]))*eps_b[b,o])
//   + KL(w), KL(b).
// S=16, B=32, IN=1024, OUT=1024.
//
// R14: restore R11 exactly (best measured: 37.7us; R12/R13 variants were neutral to
// slightly worse), plus one free locality fix: pre2's block->o mapping is XCD-aligned
// with fused's reader (o = (blk&7)*128 + (blk>>3)), so the 4MB tbl handoff stays in
// the producing XCD's L2 instead of crossing dies.
//  - tbl precomputed in MFMA-FRAG order -> k-loop tbl reads lane-contiguous (1KB/instr).
//  - eps: 512-thr blocks, K-split-8; wave = [16 rows x 128 k]: 16 coalesced dwordx2
//    row loads -> XOR-swizzled wave LDS -> 4 k-steps read B-frags from LDS.
//  - ALL global loads issue up front; (512,4); grid 2049 (block 2048 = KL finalize).

constexpr int S_ = 16, B_ = 32, IN_ = 1024, OUT_ = 1024;

typedef __bf16 bf16x8 __attribute__((ext_vector_type(8)));
typedef float  f32x4  __attribute__((ext_vector_type(4)));

__device__ __forceinline__ float softplus_f(float x) {
    float e = __expf(-fabsf(x));
    return fmaxf(x, 0.0f) + __logf(1.0f + e);
}

__device__ __forceinline__ unsigned bf16_hi(float x) {   // round, keep high 16
    return (__float_as_uint(x) + 0x8000u) & 0xffff0000u;
}

// ---------------- K1: frag-ordered packed table + klw partials (blocks 0-1023) ----
//                     input -> bf16 A-frags (blocks 1024-1055)
__global__ __launch_bounds__(256) void bpl_pre2(
    const float* __restrict__ input,   // [S,B,IN]
    const float* __restrict__ w_mu, const float* __restrict__ w_eta,
    unsigned* __restrict__ tbl_f,      // 4MB frag-ordered
    __bf16* __restrict__ a_ws,         // [B][2048][8]
    float* __restrict__ klw_part)      // [1024]
{
    const int tid = threadIdx.x;

    if (blockIdx.x >= 1024) {          // ---- A-frag staging (verified R7+) ----
        const int b = blockIdx.x - 1024;
        #pragma unroll
        for (int j = 0; j < 8; ++j) {
            const int c  = tid + j * 256;
            const int k0 = ((c >> 6) << 5) | (((c >> 4) & 3) << 3);
            const int s  = c & 15;
            const float* src = input + ((size_t)s * B_ + b) * IN_ + k0;
            const float4 x0 = *reinterpret_cast<const float4*>(src);
            const float4 x1 = *reinterpret_cast<const float4*>(src + 4);
            bf16x8 v;
            v[0] = (__bf16)x0.x; v[1] = (__bf16)x0.y; v[2] = (__bf16)x0.z; v[3] = (__bf16)x0.w;
            v[4] = (__bf16)x1.x; v[5] = (__bf16)x1.y; v[6] = (__bf16)x1.z; v[7] = (__bf16)x1.w;
            *reinterpret_cast<bf16x8*>(&a_ws[(size_t)b * 16384 + (size_t)c * 8]) = v;
        }
        return;
    }

    __shared__ float red[4];
    const int wid  = tid >> 6;
    const int lane = tid & 63;
    // XCD-aligned o mapping: this block (XCD = blk&7) owns o-row in the 128-row slice
    // that fused blocks on the SAME XCD will read (fused xcd = o>>7). Bijective.
    const int blk  = blockIdx.x;
    const int o    = ((blk & 7) << 7) | (blk >> 3);
    const int ot   = o >> 4;
    const int on   = o & 15;

    const size_t base = (size_t)o * IN_ + tid * 4;
    const float4 mu = *reinterpret_cast<const float4*>(&w_mu[base]);
    const float4 et = *reinterpret_cast<const float4*>(&w_eta[base]);
    const float m[4] = {mu.x, mu.y, mu.z, mu.w};
    const float e[4] = {et.x, et.y, et.z, et.w};

    float local = 0.0f;
    #pragma unroll
    for (int j = 0; j < 4; ++j) {
        const int   i   = tid * 4 + j;
        const float sp  = __logf(1.0f + __expf(e[j])) + 1e-6f;  // w_eta in [-4,-2]
        const float spl = sp * 1.44269504f;                      // *log2(e)
        const float emu = __expf(m[j]);
        const unsigned pk = bf16_hi(emu) | (bf16_hi(spl) >> 16);
        const int kt  = i >> 5;
        const int kg0 = (i >> 3) & 3;
        const int jj  = i & 7;
        const int ln  = kg0 * 16 + on;
        tbl_f[(((size_t)ot * 32 + kt) * 64 + ln) * 8 + jj] = pk;
        local += -__logf(sp) + 0.5f * fmaf(sp, sp, m[j] * m[j]) - 0.5f;
    }

    #pragma unroll
    for (int off = 32; off > 0; off >>= 1) local += __shfl_xor(local, off, 64);
    if (lane == 0) red[wid] = local;
    __syncthreads();
    if (tid == 0) klw_part[blk] = red[0] + red[1] + red[2] + red[3];
}

// ---------------- K2: fused GEMM (blocks 0-2047) + klfin (block 2048) ----------
__global__ __launch_bounds__(512, 4) void bpl_fused(
    const unsigned* __restrict__ tbl_f,// frag-ordered table
    const __bf16* __restrict__ a_ws,   // [B][2048][8]
    const float* __restrict__ eps_w,   // [B,OUT,IN]
    const float* __restrict__ b_mu,    // [OUT]
    const float* __restrict__ b_eta,   // [OUT]
    const float* __restrict__ eps_b,   // [B,OUT]
    const float* __restrict__ klw_part,// [1024]
    float* __restrict__ out,           // [S,B,OUT]
    float* __restrict__ kl)            // kl[0], kl[1]
{
    const int blk = blockIdx.x;
    const int tid = threadIdx.x;

    if (blk == 2048) {                 // ---- klfin (512 threads) ----
        __shared__ float kred[16];
        const int wid  = tid >> 6;
        const int lane = tid & 63;
        float lw = klw_part[tid] + klw_part[tid + 512];
        float lb;
        {
            const int o = tid;               // 0..511
            const float sd0 = softplus_f(b_eta[o]) + 1e-6f;
            const float m0  = b_mu[o];
            const float sd1 = softplus_f(b_eta[o + 512]) + 1e-6f;
            const float m1  = b_mu[o + 512];
            lb = (-__logf(sd0) + 0.5f * fmaf(sd0, sd0, m0 * m0) - 0.5f)
               + (-__logf(sd1) + 0.5f * fmaf(sd1, sd1, m1 * m1) - 0.5f);
        }
        #pragma unroll
        for (int off = 32; off > 0; off >>= 1) {
            lw += __shfl_xor(lw, off, 64);
            lb += __shfl_xor(lb, off, 64);
        }
        if (lane == 0) { kred[wid] = lw; kred[8 + wid] = lb; }
        __syncthreads();
        if (tid == 0) {
            float tw = 0.0f, tb = 0.0f;
            #pragma unroll
            for (int k = 0; k < 8; ++k) { tw += kred[k]; tb += kred[8 + k]; }
            kl[0] = tw; kl[1] = tb;
        }
        return;
    }

    __shared__ __align__(16) float smem[16384];   // 64KB: 8 waves x 8KB; reused for reduce

    const int xcd = blk & 7;
    const int r_  = blk >> 3;          // 0..255
    const int b   = r_ & 31;
    const int otl = r_ >> 5;           // 0..7
    const int o_base = xcd * 128 + otl * 16;
    const int ot_g   = o_base >> 4;    // global o-tile 0..63

    const int kq   = tid >> 6;         // 0..7: K-eighth
    const int lane = tid & 63;
    const int on   = lane & 15;
    const int kg0  = lane >> 4;        // 0..3

    // ---- issue ALL global loads up front (coalesced) ----
    const float* eps_base = eps_w + ((size_t)(b * 1024 + o_base)) * 1024 + kq * 128;
    float2 ev[16];
    #pragma unroll
    for (int r = 0; r < 16; ++r)
        ev[r] = *reinterpret_cast<const float2*>(eps_base + (size_t)r * 1024 + lane * 2);

    const unsigned* tf = tbl_f + (((size_t)ot_g * 32 + kq * 4) * 64 + lane) * 8;
    uint4 t0[4], t1[4];
    #pragma unroll
    for (int t = 0; t < 4; ++t) {
        t0[t] = *reinterpret_cast<const uint4*>(tf + t * 512);
        t1[t] = *reinterpret_cast<const uint4*>(tf + t * 512 + 4);
    }

    const __bf16* ap = a_ws + (size_t)b * 16384 + (size_t)(kq * 4) * 512 + lane * 8;
    bf16x8 av[4];
    #pragma unroll
    for (int t = 0; t < 4; ++t)
        av[t] = *reinterpret_cast<const bf16x8*>(ap + t * 512);

    // ---- stage eps into wave-local LDS (8KB), XOR-swizzled rows ----
    char* wbase = (char*)(smem + kq * 2048);      // 8KB per wave
    #pragma unroll
    for (int r = 0; r < 16; ++r) {
        const int byte = (lane * 8) ^ ((r & 7) << 4);
        *reinterpret_cast<float2*>(wbase + r * 512 + byte) = ev[r];
    }
    __syncthreads();

    // ---- 4 k-steps: LDS B-frag + reg tbl/a -> MFMA ----
    f32x4 acc = {0.0f, 0.0f, 0.0f, 0.0f};
    const int sw = (on & 7) << 4;
    #pragma unroll
    for (int t = 0; t < 4; ++t) {
        const f32x4 e0 = *reinterpret_cast<const f32x4*>(
            wbase + on * 512 + (((t * 128 + kg0 * 32)) ^ sw));
        const f32x4 e1 = *reinterpret_cast<const f32x4*>(
            wbase + on * 512 + (((t * 128 + kg0 * 32 + 16)) ^ sw));

        const unsigned uu[8] = {t0[t].x, t0[t].y, t0[t].z, t0[t].w,
                                t1[t].x, t1[t].y, t1[t].z, t1[t].w};
        const float    ee[8] = {e0[0], e0[1], e0[2], e0[3], e1[0], e1[1], e1[2], e1[3]};

        bf16x8 bfrag;
        #pragma unroll
        for (int q = 0; q < 8; ++q) {
            const float emu = __uint_as_float(uu[q] & 0xffff0000u);
            const float spl = __uint_as_float(uu[q] << 16);
            bfrag[q] = (__bf16)(emu * exp2f(spl * ee[q]));
        }
        acc = __builtin_amdgcn_mfma_f32_16x16x32_bf16(av[t], bfrag, acc, 0, 0, 0);
    }

    // ---- reduce 8 K-partials via LDS (overlay on eps region) ----
    __syncthreads();                   // all eps reads done
    *reinterpret_cast<f32x4*>(&smem[(kq * 64 + lane) * 4]) = acc;
    __syncthreads();

    if (tid < 256) {
        const int s  = tid >> 4;       // 0..15
        const int ol = tid & 15;
        const int srcLane = ((s >> 2) << 4) | ol;
        const int rr = s & 3;
        float v = 0.0f;
        #pragma unroll
        for (int k8 = 0; k8 < 8; ++k8)
            v += smem[((k8 * 64 + srcLane) * 4) + rr];
        const int oo = o_base + ol;
        const float bias = fmaf(softplus_f(b_eta[oo]) + 1e-6f,
                                eps_b[(size_t)b * OUT_ + oo], b_mu[oo]);
        out[((size_t)s * B_ + b) * OUT_ + oo] = v + bias;
    }
}

// ---------------- fallback (R6/R7 verified path, no ws) ----------------
__global__ __launch_bounds__(256) void bpl_pre_fb(
    const float* __restrict__ w_mu, const float* __restrict__ w_eta,
    const float* __restrict__ b_mu, const float* __restrict__ b_eta,
    float* __restrict__ kl)
{
    __shared__ float red[4];
    const int tid  = threadIdx.x;
    const int wid  = tid >> 6;
    const int lane = tid & 63;

    const size_t base = (size_t)blockIdx.x * IN_ + tid * 4;
    const float4 mu = *reinterpret_cast<const float4*>(&w_mu[base]);
    const float4 et = *reinterpret_cast<const float4*>(&w_eta[base]);
    const float m[4] = {mu.x, mu.y, mu.z, mu.w};
    const float e[4] = {et.x, et.y, et.z, et.w};

    float local = 0.0f;
    #pragma unroll
    for (int j = 0; j < 4; ++j) {
        const float sp = __logf(1.0f + __expf(e[j])) + 1e-6f;
        local += -__logf(sp) + 0.5f * fmaf(sp, sp, m[j] * m[j]) - 0.5f;
    }
    #pragma unroll
    for (int off = 32; off > 0; off >>= 1) local += __shfl_xor(local, off, 64);
    if (lane == 0) red[wid] = local;
    __syncthreads();
    if (tid == 0) atomicAdd(&kl[0], red[0] + red[1] + red[2] + red[3]);

    if (blockIdx.x != 0) return;
    float lb = 0.0f;
    #pragma unroll
    for (int j = 0; j < 4; ++j) {
        const int idx = tid * 4 + j;
        const float sd = softplus_f(b_eta[idx]) + 1e-6f;
        const float mm = b_mu[idx];
        lb += -__logf(sd) + 0.5f * fmaf(sd, sd, mm * mm) - 0.5f;
    }
    #pragma unroll
    for (int off = 32; off > 0; off >>= 1) lb += __shfl_xor(lb, off, 64);
    __syncthreads();
    if (lane == 0) red[wid] = lb;
    __syncthreads();
    if (tid == 0) atomicAdd(&kl[1], red[0] + red[1] + red[2] + red[3]);
}

__global__ __launch_bounds__(256, 4) void bpl_mfma_fb(
    const float* __restrict__ input, const float* __restrict__ w_mu,
    const float* __restrict__ w_eta, const float* __restrict__ b_mu,
    const float* __restrict__ b_eta, const float* __restrict__ eps_w,
    const float* __restrict__ eps_b, float* __restrict__ out)
{
    __shared__ __align__(16) __bf16 alds[16384];

    const int blk = blockIdx.x;
    const int xcd = blk & 7;
    const int r_  = blk >> 3;
    const int b   = r_ & 31;
    const int oh  = r_ >> 5;
    const int o_base = (xcd * 2 + oh) * 64;

    const int tid  = threadIdx.x;
    const int wid  = tid >> 6;
    const int lane = tid & 63;

    #pragma unroll
    for (int j = 0; j < 8; ++j) {
        const int c   = tid + j * 256;
        const int s   = c & 15;
        const int kgg = ((c >> 6) << 2) | ((c >> 4) & 3);
        const float* src = input + ((size_t)s * B_ + b) * IN_ + kgg * 8;
        const float4 x0 = *reinterpret_cast<const float4*>(src);
        const float4 x1 = *reinterpret_cast<const float4*>(src + 4);
        bf16x8 v;
        v[0] = (__bf16)x0.x; v[1] = (__bf16)x0.y; v[2] = (__bf16)x0.z; v[3] = (__bf16)x0.w;
        v[4] = (__bf16)x1.x; v[5] = (__bf16)x1.y; v[6] = (__bf16)x1.z; v[7] = (__bf16)x1.w;
        *reinterpret_cast<bf16x8*>(&alds[c * 8]) = v;
    }
    __syncthreads();

    const int on    = lane & 15;
    const int kg0   = lane >> 4;
    const int o_row = o_base + wid * 16 + on;

    const float* __restrict__ mu_p = w_mu  + (size_t)o_row * IN_ + kg0 * 8;
    const float* __restrict__ et_p = w_eta + (size_t)o_row * IN_ + kg0 * 8;
    const float* __restrict__ ep_p = eps_w + ((size_t)b * OUT_ + o_row) * IN_ + kg0 * 8;
    const __bf16* __restrict__ a_p = alds + lane * 8;

    f32x4 acc = {0.0f, 0.0f, 0.0f, 0.0f};
    #pragma unroll
    for (int kt = 0; kt < 32; ++kt) {
        const int i_ = kt * 32;
        const float4 m0 = *reinterpret_cast<const float4*>(mu_p + i_);
        const float4 m1 = *reinterpret_cast<const float4*>(mu_p + i_ + 4);
        const float4 s0 = *reinterpret_cast<const float4*>(et_p + i_);
        const float4 s1 = *reinterpret_cast<const float4*>(et_p + i_ + 4);
        const float4 e0 = *reinterpret_cast<const float4*>(ep_p + i_);
        const float4 e1 = *reinterpret_cast<const float4*>(ep_p + i_ + 4);
        const float mm[8] = {m0.x, m0.y, m0.z, m0.w, m1.x, m1.y, m1.z, m1.w};
        const float ss[8] = {s0.x, s0.y, s0.z, s0.w, s1.x, s1.y, s1.z, s1.w};
        const float ee[8] = {e0.x, e0.y, e0.z, e0.w, e1.x, e1.y, e1.z, e1.w};
        bf16x8 bfrag;
        #pragma unroll
        for (int q = 0; q < 8; ++q) {
            const float sp_ = __logf(1.0f + __expf(ss[q])) + 1e-6f;
            bfrag[q] = (__bf16)__expf(fmaf(sp_, ee[q], mm[q]));
        }
        const bf16x8 afrag = *reinterpret_cast<const bf16x8*>(a_p + kt * 512);
        acc = __builtin_amdgcn_mfma_f32_16x16x32_bf16(afrag, bfrag, acc, 0, 0, 0);
    }

    const float bias = fmaf(softplus_f(b_eta[o_row]) + 1e-6f,
                            eps_b[(size_t)b * OUT_ + o_row], b_mu[o_row]);
    #pragma unroll
    for (int rr = 0; rr < 4; ++rr) {
        const int s = kg0 * 4 + rr;
        out[((size_t)s * B_ + b) * OUT_ + o_row] = acc[rr] + bias;
    }
}

extern "C" void kernel_launch(void* const* d_in, const int* in_sizes, int n_in,
                              void* d_out, int out_size, void* d_ws, size_t ws_size,
                              hipStream_t stream)
{
    const float* input = (const float*)d_in[0];
    const float* w_mu  = (const float*)d_in[1];
    const float* w_eta = (const float*)d_in[2];
    const float* b_mu  = (const float*)d_in[3];
    const float* b_eta = (const float*)d_in[4];
    const float* eps_w = (const float*)d_in[5];
    const float* eps_b = (const float*)d_in[6];

    float* out = (float*)d_out;
    float* kl  = out + (size_t)S_ * B_ * OUT_;   // offsets 524288, 524289

    // ws layout
    const size_t TBL_OFF = 0;                                  // 4 MB frag-ordered table
    const size_t A_OFF   = (size_t)4 * 1024 * 1024;            // 1 MB bf16 a-frags
    const size_t KLP_OFF = (size_t)5 * 1024 * 1024;            // 4 KB kl_w partials
    const size_t NEED    = KLP_OFF + 4096;

    if (ws_size >= NEED) {
        unsigned* tbl  = (unsigned*)((char*)d_ws + TBL_OFF);
        __bf16*   a_ws = (__bf16*)((char*)d_ws + A_OFF);
        float*    klp  = (float*)((char*)d_ws + KLP_OFF);

        bpl_pre2<<<1056, 256, 0, stream>>>(input, w_mu, w_eta, tbl, a_ws, klp);
        bpl_fused<<<2049, 512, 0, stream>>>(tbl, a_ws, eps_w, b_mu, b_eta, eps_b,
                                            klp, out, kl);
    } else {
        hipMemsetAsync(kl, 0, 2 * sizeof(float), stream);
        bpl_pre_fb<<<1024, 256, 0, stream>>>(w_mu, w_eta, b_mu, b_eta, kl);
        bpl_mfma_fb<<<512, 256, 0, stream>>>(input, w_mu, w_eta, b_mu, b_eta,
                                             eps_w, eps_b, out);
    }
}